// Round 2
// baseline (529.538 us; speedup 1.0000x reference)
//
#include <hip/hip_runtime.h>

// Problem constants
#define Bq 16
#define Tq 12
#define Nq 512
#define Dq 128
#define BTq (Bq * Tq)       // 192
#define ROWSq (BTq * Nq)    // 98304 rows of [D]

// Workspace layout (floats):
//   qn   [ROWS][128]
//   kn   [ROWS][128]
//   vv   [ROWS][128]
//   ksum [16][128]
//   ms   [192][128][128]   M_s = Kn^T V  per (b,t)
//   mt   [192][128][128]   M_t = Qn^T V  per (b,t)
//   gs   [192][128][128]   Gs = M_s @ Fs^T   (layout [e][o])
//   gt   [192][128][128]   Gt = M_t @ Ft^T
//   gv   [128][128]        Gv[d][o] = T * (Fs[o][d] + Ft[o][d])
// total = 50,350,080 floats = 201.4 MB

__device__ __forceinline__ void fma4(float4& c, float a, const float4& b) {
  c.x = fmaf(a, b.x, c.x);
  c.y = fmaf(a, b.y, c.y);
  c.z = fmaf(a, b.z, c.z);
  c.w = fmaf(a, b.w, c.w);
}

__device__ __forceinline__ void scale4(float4& c, float s) {
  c.x *= s; c.y *= s; c.z *= s; c.w *= s;
}

__global__ void zero_kernel(float* __restrict__ p, int n) {
  int i = blockIdx.x * blockDim.x + threadIdx.x;
  if (i < n) p[i] = 0.0f;
}

// ---------------------------------------------------------------------------
// Stage 1: Q/K/V projection (+ L2 normalize for Q,K; Ksum atomics for K)
// grid = (ROWS/64, 3) z: 0=Q 1=K 2=V ; block = 256
// C[m][e] = sum_d h[m][d] * W[e][d]
// ---------------------------------------------------------------------------
__global__ __launch_bounds__(256) void proj_kernel(
    const float* __restrict__ h,
    const float* __restrict__ Wq, const float* __restrict__ Wk, const float* __restrict__ Wv,
    float* __restrict__ qn, float* __restrict__ kn, float* __restrict__ vv,
    float* __restrict__ ksum)
{
  const int z = blockIdx.y;
  const int row0 = blockIdx.x * 64;
  const float* __restrict__ W = (z == 0) ? Wq : (z == 1) ? Wk : Wv;
  float* __restrict__ outp = (z == 0) ? qn : (z == 1) ? kn : vv;

  __shared__ float hs[64][33];    // [row][k] pad-33: conflict-free scalar reads
  __shared__ float wsm[32][128];  // [k][e] transposed; b128 reads at 4tx+32g hit distinct quads
  __shared__ float pss[64][8];
  __shared__ float invn[64];
  __shared__ float colsum[128];

  const int tid = threadIdx.x;
  const int ty = tid >> 3;  // 0..31 -> rows 2ty, 2ty+1
  const int tx = tid & 7;   // 0..7  -> col groups 4tx + 32g
  const int r0 = ty * 2;

  float4 c0[4], c1[4];
#pragma unroll
  for (int g = 0; g < 4; ++g) {
    c0[g] = make_float4(0.f, 0.f, 0.f, 0.f);
    c1[g] = make_float4(0.f, 0.f, 0.f, 0.f);
  }

  for (int kc = 0; kc < 4; ++kc) {
    const int d0 = kc * 32;
    // h tile 64x32 (coalesced: each 8-lane group reads 128B contiguous)
    for (int s = tid; s < 512; s += 256) {
      const int row = s >> 3, j = s & 7;
      const float4 v = *(const float4*)(h + (size_t)(row0 + row) * 128 + d0 + 4 * j);
      hs[row][4 * j + 0] = v.x; hs[row][4 * j + 1] = v.y;
      hs[row][4 * j + 2] = v.z; hs[row][4 * j + 3] = v.w;
    }
    // W tile transposed: wsm[k][e] = W[e][d0+k]
    for (int s = tid; s < 1024; s += 256) {
      const int e = s >> 3, j = s & 7;
      const float4 v = *(const float4*)(W + (size_t)e * 128 + d0 + 4 * j);
      wsm[4 * j + 0][e] = v.x; wsm[4 * j + 1][e] = v.y;
      wsm[4 * j + 2][e] = v.z; wsm[4 * j + 3][e] = v.w;
    }
    __syncthreads();
#pragma unroll 8
    for (int kk = 0; kk < 32; ++kk) {
      const float a0 = hs[r0][kk];
      const float a1 = hs[r0 + 1][kk];
      const float4* wr = (const float4*)&wsm[kk][0];
      const float4 w0 = wr[tx];
      const float4 w1 = wr[tx + 8];
      const float4 w2 = wr[tx + 16];
      const float4 w3 = wr[tx + 24];
      fma4(c0[0], a0, w0); fma4(c0[1], a0, w1); fma4(c0[2], a0, w2); fma4(c0[3], a0, w3);
      fma4(c1[0], a1, w0); fma4(c1[1], a1, w1); fma4(c1[2], a1, w2); fma4(c1[3], a1, w3);
    }
    __syncthreads();
  }

  if (z < 2) {
    // L2 norm over each row (reduce partial sums-of-squares across the 8 tx)
    float p0 = 0.f, p1 = 0.f;
#pragma unroll
    for (int g = 0; g < 4; ++g) {
      p0 += c0[g].x * c0[g].x + c0[g].y * c0[g].y + c0[g].z * c0[g].z + c0[g].w * c0[g].w;
      p1 += c1[g].x * c1[g].x + c1[g].y * c1[g].y + c1[g].z * c1[g].z + c1[g].w * c1[g].w;
    }
    pss[r0][tx] = p0;
    pss[r0 + 1][tx] = p1;
    __syncthreads();
    if (tid < 64) {
      float s = 0.f;
#pragma unroll
      for (int x = 0; x < 8; ++x) s += pss[tid][x];
      invn[tid] = 1.0f / fmaxf(sqrtf(s), 1e-12f);
    }
    __syncthreads();
    const float i0 = invn[r0], i1 = invn[r0 + 1];
#pragma unroll
    for (int g = 0; g < 4; ++g) { scale4(c0[g], i0); scale4(c1[g], i1); }
  }

#pragma unroll
  for (int g = 0; g < 4; ++g) {
    *(float4*)(outp + (size_t)(row0 + r0) * 128 + 4 * tx + 32 * g) = c0[g];
    *(float4*)(outp + (size_t)(row0 + r0 + 1) * 128 + 4 * tx + 32 * g) = c1[g];
  }

  if (z == 1) {
    // Ksum[b][e] += column sums of this 64-row Kn tile
    __syncthreads();
    if (tid < 128) colsum[tid] = 0.f;
    __syncthreads();
#pragma unroll
    for (int g = 0; g < 4; ++g) {
      const int cbase = 4 * tx + 32 * g;
      atomicAdd(&colsum[cbase + 0], c0[g].x + c1[g].x);
      atomicAdd(&colsum[cbase + 1], c0[g].y + c1[g].y);
      atomicAdd(&colsum[cbase + 2], c0[g].z + c1[g].z);
      atomicAdd(&colsum[cbase + 3], c0[g].w + c1[g].w);
    }
    __syncthreads();
    if (tid < 128) {
      const int b = blockIdx.x / 96;  // 6144 rows per b / 64 rows per block
      atomicAdd(ksum + (size_t)b * 128 + tid, colsum[tid]);
    }
  }
}

// ---------------------------------------------------------------------------
// Stage 2: per-(b,t) rank reductions. grid = (192, 2); z=0: M_s=Kn^T V, z=1: M_t=Qn^T V
// M[e][d] = sum_{m<512} X[m][e] * V[m][d]
// ---------------------------------------------------------------------------
__global__ __launch_bounds__(256) void outer_kernel(
    const float* __restrict__ qn, const float* __restrict__ kn, const float* __restrict__ vv,
    float* __restrict__ ms, float* __restrict__ mt)
{
  const int bt = blockIdx.x;
  const int z = blockIdx.y;
  const float* __restrict__ X = ((z == 0) ? kn : qn) + (size_t)bt * 512 * 128;
  const float* __restrict__ V = vv + (size_t)bt * 512 * 128;
  float* __restrict__ outp = ((z == 0) ? ms : mt) + (size_t)bt * 128 * 128;

  __shared__ float xs[32][128];
  __shared__ float vs[32][128];

  const int tid = threadIdx.x;
  const int ty = tid >> 4;  // e groups: 4ty + 64eg
  const int tx = tid & 15;  // d groups: 4tx + 64dg

  float4 acc[2][4][2];  // [eg][ei][dg]
#pragma unroll
  for (int eg = 0; eg < 2; ++eg)
#pragma unroll
    for (int ei = 0; ei < 4; ++ei)
#pragma unroll
      for (int dg = 0; dg < 2; ++dg) acc[eg][ei][dg] = make_float4(0.f, 0.f, 0.f, 0.f);

  for (int m0 = 0; m0 < 512; m0 += 32) {
    for (int s = tid; s < 1024; s += 256) {
      const int mm = s >> 5, j = s & 31;
      *(float4*)&xs[mm][4 * j] = *(const float4*)(X + (size_t)(m0 + mm) * 128 + 4 * j);
      *(float4*)&vs[mm][4 * j] = *(const float4*)(V + (size_t)(m0 + mm) * 128 + 4 * j);
    }
    __syncthreads();
#pragma unroll 4
    for (int mm = 0; mm < 32; ++mm) {
      const float4 xe0 = *(const float4*)&xs[mm][4 * ty];
      const float4 xe1 = *(const float4*)&xs[mm][4 * ty + 64];
      const float4 vd0 = *(const float4*)&vs[mm][4 * tx];
      const float4 vd1 = *(const float4*)&vs[mm][4 * tx + 64];
      const float xe[8] = {xe0.x, xe0.y, xe0.z, xe0.w, xe1.x, xe1.y, xe1.z, xe1.w};
#pragma unroll
      for (int eg = 0; eg < 2; ++eg)
#pragma unroll
        for (int ei = 0; ei < 4; ++ei) {
          fma4(acc[eg][ei][0], xe[eg * 4 + ei], vd0);
          fma4(acc[eg][ei][1], xe[eg * 4 + ei], vd1);
        }
    }
    __syncthreads();
  }

#pragma unroll
  for (int eg = 0; eg < 2; ++eg)
#pragma unroll
    for (int ei = 0; ei < 4; ++ei) {
      const int e = 4 * ty + 64 * eg + ei;
      *(float4*)(outp + (size_t)e * 128 + 4 * tx) = acc[eg][ei][0];
      *(float4*)(outp + (size_t)e * 128 + 4 * tx + 64) = acc[eg][ei][1];
    }
}

// ---------------------------------------------------------------------------
// Stage 3: G matrices. grid = 2*192 + 1.
//   g<384:  G[e][o] = sum_d M[e][d] * F[o][d],  F = fc_w[:, z*128 : z*128+128]
//   g==384: Gv[d][o] = T * (Fs[o][d] + Ft[o][d])
// ---------------------------------------------------------------------------
__global__ __launch_bounds__(256) void gmat_kernel(
    const float* __restrict__ ms, const float* __restrict__ mt,
    const float* __restrict__ fcw,
    float* __restrict__ gs, float* __restrict__ gt, float* __restrict__ gv)
{
  const int g = blockIdx.x;
  const int tid = threadIdx.x;
  if (g == 2 * BTq) {
    for (int i = tid; i < 128 * 128; i += 256) {
      const int d = i >> 7, o = i & 127;
      gv[i] = (float)Tq * (fcw[(size_t)o * 256 + d] + fcw[(size_t)o * 256 + 128 + d]);
    }
    return;
  }
  const int bt = g >> 1, z = g & 1;
  const float* __restrict__ M = ((z == 0) ? ms : mt) + (size_t)bt * 16384;
  float* __restrict__ G = ((z == 0) ? gs : gt) + (size_t)bt * 16384;
  const float* __restrict__ F = fcw + z * 128;  // F[o][d] = fcw[o*256 + z*128 + d]

  __shared__ float mls[32][128];  // mls[k][e] = M[e][d0+k]
  __shared__ float fls[32][128];  // fls[k][o] = F[o][d0+k]

  const int ty = tid >> 4, tx = tid & 15;

  float4 acc[2][4][2];  // [eg][ei][og]
#pragma unroll
  for (int eg = 0; eg < 2; ++eg)
#pragma unroll
    for (int ei = 0; ei < 4; ++ei)
#pragma unroll
      for (int og = 0; og < 2; ++og) acc[eg][ei][og] = make_float4(0.f, 0.f, 0.f, 0.f);

  for (int d0 = 0; d0 < 128; d0 += 32) {
    for (int s = tid; s < 1024; s += 256) {
      const int e = s >> 3, j = s & 7;
      const float4 mv = *(const float4*)(M + (size_t)e * 128 + d0 + 4 * j);
      mls[4 * j + 0][e] = mv.x; mls[4 * j + 1][e] = mv.y;
      mls[4 * j + 2][e] = mv.z; mls[4 * j + 3][e] = mv.w;
      const float4 fv = *(const float4*)(F + (size_t)e * 256 + d0 + 4 * j);
      fls[4 * j + 0][e] = fv.x; fls[4 * j + 1][e] = fv.y;
      fls[4 * j + 2][e] = fv.z; fls[4 * j + 3][e] = fv.w;
    }
    __syncthreads();
#pragma unroll 4
    for (int dd = 0; dd < 32; ++dd) {
      const float4 me0 = *(const float4*)&mls[dd][4 * ty];
      const float4 me1 = *(const float4*)&mls[dd][4 * ty + 64];
      const float4 fo0 = *(const float4*)&fls[dd][4 * tx];
      const float4 fo1 = *(const float4*)&fls[dd][4 * tx + 64];
      const float me[8] = {me0.x, me0.y, me0.z, me0.w, me1.x, me1.y, me1.z, me1.w};
#pragma unroll
      for (int eg = 0; eg < 2; ++eg)
#pragma unroll
        for (int ei = 0; ei < 4; ++ei) {
          fma4(acc[eg][ei][0], me[eg * 4 + ei], fo0);
          fma4(acc[eg][ei][1], me[eg * 4 + ei], fo1);
        }
    }
    __syncthreads();
  }

#pragma unroll
  for (int eg = 0; eg < 2; ++eg)
#pragma unroll
    for (int ei = 0; ei < 4; ++ei) {
      const int e = 4 * ty + 64 * eg + ei;
      *(float4*)(G + (size_t)e * 128 + 4 * tx) = acc[eg][ei][0];
      *(float4*)(G + (size_t)e * 128 + 4 * tx + 64) = acc[eg][ei][1];
    }
}

// ---------------------------------------------------------------------------
// Stage 4: final fused output. grid = ROWS/64 = 1536; block = 256.
// out[row][o] = (Qn[row]·Gs[:,o] + Kn[row]·Gt[:,o] + V[row]·Gv[:,o]) / ((Qn·Ksum[b] + T)*N) + fc_b[o]
// ---------------------------------------------------------------------------
__global__ __launch_bounds__(256) void out_kernel(
    const float* __restrict__ qn, const float* __restrict__ kn, const float* __restrict__ vv,
    const float* __restrict__ gs, const float* __restrict__ gt, const float* __restrict__ gvp,
    const float* __restrict__ ksum, const float* __restrict__ fcb,
    float* __restrict__ outp)
{
  const int bid = blockIdx.x;
  const int bt = bid >> 3;
  const int sub = bid & 7;
  const size_t row0 = (size_t)bt * 512 + (size_t)sub * 64;
  const int b = bt / Tq;
  const float* __restrict__ Gs = gs + (size_t)bt * 16384;
  const float* __restrict__ Gt = gt + (size_t)bt * 16384;

  __shared__ float qs[64][33], ks2[64][33], vs2[64][33];
  __shared__ float gsl[32][128], gtl[32][128], gvl[32][128];
  __shared__ float ksl[128], fbl[128];

  const int tid = threadIdx.x;
  const int ty = tid >> 4, tx = tid & 15;
  const int r0 = ty * 4;

  if (tid < 128) {
    ksl[tid] = ksum[(size_t)b * 128 + tid];
    fbl[tid] = fcb[tid];
  }

  float4 acc[4][2];
  float dn[4] = {0.f, 0.f, 0.f, 0.f};
#pragma unroll
  for (int i = 0; i < 4; ++i) {
    acc[i][0] = make_float4(0.f, 0.f, 0.f, 0.f);
    acc[i][1] = make_float4(0.f, 0.f, 0.f, 0.f);
  }

  for (int kc = 0; kc < 4; ++kc) {
    const int d0 = kc * 32;
    for (int s = tid; s < 512; s += 256) {
      const int row = s >> 3, j = s & 7;
      const size_t gbase = (row0 + row) * 128 + d0 + 4 * j;
      const float4 q4 = *(const float4*)(qn + gbase);
      qs[row][4 * j + 0] = q4.x; qs[row][4 * j + 1] = q4.y;
      qs[row][4 * j + 2] = q4.z; qs[row][4 * j + 3] = q4.w;
      const float4 k4 = *(const float4*)(kn + gbase);
      ks2[row][4 * j + 0] = k4.x; ks2[row][4 * j + 1] = k4.y;
      ks2[row][4 * j + 2] = k4.z; ks2[row][4 * j + 3] = k4.w;
      const float4 v4 = *(const float4*)(vv + gbase);
      vs2[row][4 * j + 0] = v4.x; vs2[row][4 * j + 1] = v4.y;
      vs2[row][4 * j + 2] = v4.z; vs2[row][4 * j + 3] = v4.w;
    }
    for (int s = tid; s < 1024; s += 256) {
      const int kk2 = s >> 5, j = s & 31;
      *(float4*)&gsl[kk2][4 * j] = *(const float4*)(Gs + (size_t)(d0 + kk2) * 128 + 4 * j);
      *(float4*)&gtl[kk2][4 * j] = *(const float4*)(Gt + (size_t)(d0 + kk2) * 128 + 4 * j);
      *(float4*)&gvl[kk2][4 * j] = *(const float4*)(gvp + (size_t)(d0 + kk2) * 128 + 4 * j);
    }
    __syncthreads();
#pragma unroll 4
    for (int kk = 0; kk < 32; ++kk) {
      const float ksv = ksl[d0 + kk];
      const float4 s0 = *(const float4*)&gsl[kk][4 * tx];
      const float4 s1 = *(const float4*)&gsl[kk][4 * tx + 64];
      const float4 t0 = *(const float4*)&gtl[kk][4 * tx];
      const float4 t1 = *(const float4*)&gtl[kk][4 * tx + 64];
      const float4 u0 = *(const float4*)&gvl[kk][4 * tx];
      const float4 u1 = *(const float4*)&gvl[kk][4 * tx + 64];
#pragma unroll
      for (int i = 0; i < 4; ++i) {
        const float qv = qs[r0 + i][kk];
        const float kv = ks2[r0 + i][kk];
        const float vw = vs2[r0 + i][kk];
        dn[i] = fmaf(qv, ksv, dn[i]);
        fma4(acc[i][0], qv, s0); fma4(acc[i][1], qv, s1);
        fma4(acc[i][0], kv, t0); fma4(acc[i][1], kv, t1);
        fma4(acc[i][0], vw, u0); fma4(acc[i][1], vw, u1);
      }
    }
    __syncthreads();
  }

#pragma unroll
  for (int i = 0; i < 4; ++i) {
    const float inv = 1.0f / ((dn[i] + (float)Tq) * (float)Nq);
    float4 o0 = acc[i][0], o1 = acc[i][1];
    o0.x = fmaf(o0.x, inv, fbl[4 * tx + 0]);
    o0.y = fmaf(o0.y, inv, fbl[4 * tx + 1]);
    o0.z = fmaf(o0.z, inv, fbl[4 * tx + 2]);
    o0.w = fmaf(o0.w, inv, fbl[4 * tx + 3]);
    o1.x = fmaf(o1.x, inv, fbl[4 * tx + 64 + 0]);
    o1.y = fmaf(o1.y, inv, fbl[4 * tx + 64 + 1]);
    o1.z = fmaf(o1.z, inv, fbl[4 * tx + 64 + 2]);
    o1.w = fmaf(o1.w, inv, fbl[4 * tx + 64 + 3]);
    *(float4*)(outp + (row0 + r0 + i) * 128 + 4 * tx) = o0;
    *(float4*)(outp + (row0 + r0 + i) * 128 + 4 * tx + 64) = o1;
  }
}

extern "C" void kernel_launch(void* const* d_in, const int* in_sizes, int n_in,
                              void* d_out, int out_size, void* d_ws, size_t ws_size,
                              hipStream_t stream) {
  (void)in_sizes; (void)n_in; (void)out_size; (void)ws_size;
  const float* h   = (const float*)d_in[0];
  const float* Wq  = (const float*)d_in[1];
  const float* Wk  = (const float*)d_in[2];
  const float* Wv  = (const float*)d_in[3];
  const float* fcw = (const float*)d_in[4];
  const float* fcb = (const float*)d_in[5];
  float* outp = (float*)d_out;
  float* ws = (float*)d_ws;

  const size_t RD = (size_t)ROWSq * Dq;        // 12,582,912
  const size_t MM = (size_t)BTq * Dq * Dq;     // 3,145,728
  float* qn = ws;
  float* kn = qn + RD;
  float* vv = kn + RD;
  float* ksum = vv + RD;                       // 2048 floats
  float* ms = ksum + (size_t)Bq * Dq;
  float* mt = ms + MM;
  float* gs = mt + MM;
  float* gt = gs + MM;
  float* gv = gt + MM;                         // 16384 floats

  zero_kernel<<<8, 256, 0, stream>>>(ksum, Bq * Dq);
  proj_kernel<<<dim3(ROWSq / 64, 3), 256, 0, stream>>>(h, Wq, Wk, Wv, qn, kn, vv, ksum);
  outer_kernel<<<dim3(BTq, 2), 256, 0, stream>>>(qn, kn, vv, ms, mt);
  gmat_kernel<<<2 * BTq + 1, 256, 0, stream>>>(ms, mt, fcw, gs, gt, gv);
  out_kernel<<<ROWSq / 64, 256, 0, stream>>>(qn, kn, vv, gs, gt, gv, ksum, fcb, outp);
}